// Round 1
// baseline (10978.715 us; speedup 1.0000x reference)
//
#include <hip/hip_runtime.h>

#define B_ 32
#define T_ 512
#define N_ 512
#define H_ 1024
#define O_ 512

// ---------------------------------------------------------------------------
// GEMM: C[m,n] = sum_k A[m,k] * Bt[n,k] + bias[n]
// A: M x K row-major, Bt: N x K row-major (both K-contiguous).
// 128x128 tile, BK=16, 256 threads, 8x8 per-thread micro-tile.
// ---------------------------------------------------------------------------
__global__ __launch_bounds__(256)
void gemm_bt_f32(const float* __restrict__ A, const float* __restrict__ Bt,
                 const float* __restrict__ bias, float* __restrict__ C,
                 int M, int N, int K) {
  __shared__ __align__(16) float As[16][128];
  __shared__ __align__(16) float Bs[16][128];
  const int tid = threadIdx.x;
  const int m0 = blockIdx.x * 128;
  const int n0 = blockIdx.y * 128;
  const int tr = tid >> 4;  // 0..15 row group (lane-major is tc -> coalesced C stores)
  const int tc = tid & 15;  // 0..15 col group

  float acc[8][8];
#pragma unroll
  for (int i = 0; i < 8; ++i)
#pragma unroll
    for (int j = 0; j < 8; ++j) acc[i][j] = 0.f;

  for (int k0 = 0; k0 < K; k0 += 16) {
#pragma unroll
    for (int r = 0; r < 2; ++r) {
      const int Q = tid + r * 256;       // 512 float4 quads per tile
      const int row = Q >> 2;            // 0..127
      const int kq = Q & 3;              // 0..3
      const float4 av =
          *reinterpret_cast<const float4*>(&A[(size_t)(m0 + row) * K + k0 + kq * 4]);
      As[kq * 4 + 0][row] = av.x;
      As[kq * 4 + 1][row] = av.y;
      As[kq * 4 + 2][row] = av.z;
      As[kq * 4 + 3][row] = av.w;
      const float4 bv =
          *reinterpret_cast<const float4*>(&Bt[(size_t)(n0 + row) * K + k0 + kq * 4]);
      Bs[kq * 4 + 0][row] = bv.x;
      Bs[kq * 4 + 1][row] = bv.y;
      Bs[kq * 4 + 2][row] = bv.z;
      Bs[kq * 4 + 3][row] = bv.w;
    }
    __syncthreads();
#pragma unroll
    for (int kk = 0; kk < 16; ++kk) {
      float a[8], b[8];
      *(float4*)&a[0] = *(const float4*)&As[kk][tr * 8];
      *(float4*)&a[4] = *(const float4*)&As[kk][tr * 8 + 4];
      *(float4*)&b[0] = *(const float4*)&Bs[kk][tc * 8];
      *(float4*)&b[4] = *(const float4*)&Bs[kk][tc * 8 + 4];
#pragma unroll
      for (int i = 0; i < 8; ++i)
#pragma unroll
        for (int j = 0; j < 8; ++j) acc[i][j] = fmaf(a[i], b[j], acc[i][j]);
    }
    __syncthreads();
  }

  float br[8];
#pragma unroll
  for (int j = 0; j < 8; ++j) br[j] = bias[n0 + tc * 8 + j];
#pragma unroll
  for (int i = 0; i < 8; ++i) {
    float4 s0, s1;
    s0.x = acc[i][0] + br[0];
    s0.y = acc[i][1] + br[1];
    s0.z = acc[i][2] + br[2];
    s0.w = acc[i][3] + br[3];
    s1.x = acc[i][4] + br[4];
    s1.y = acc[i][5] + br[5];
    s1.z = acc[i][6] + br[6];
    s1.w = acc[i][7] + br[7];
    float* cp = &C[(size_t)(m0 + tr * 8 + i) * N + n0 + tc * 8];
    *(float4*)cp = s0;
    *(float4*)(cp + 4) = s1;
  }
}

// ---------------------------------------------------------------------------
// Elman recurrence with circulant weight, one block per batch element.
// xz: [B,T,H] — holds x_proj on entry, overwritten in place with z_seq.
// h_ext[j] = h[(j-512) mod 1024], j in [0,2048): window read h_ext[o+k] is
// contiguous; max index = 1023+1023 = 2046 (loads reach 2047 exactly).
// Thread (g,u): outputs o = 8u..8u+7, k in [128g, 128g+128). 8 FMA per LDS
// f32 read -> VALU-bound. Partial k-sums reduced through LDS.
// ---------------------------------------------------------------------------
__global__ __launch_bounds__(1024)
void elman_recurrence(float* __restrict__ xz, const float* __restrict__ h0,
                      const float* __restrict__ w) {
  __shared__ __align__(16) float h_ext[2048];
  __shared__ __align__(16) float w_lds[1024];
  __shared__ __align__(16) float partial[8][1024];

  const int b = blockIdx.x;
  const int tid = threadIdx.x;
  const int g = __builtin_amdgcn_readfirstlane(tid >> 7);  // wave-uniform 0..7
  const int u = tid & 127;                                 // 0..127
  const int obase = u * 8;
  const int kbase = g * 128;

  // stage w and h0
  w_lds[tid] = w[tid];
  {
    const float hv = h0[b * H_ + tid];
    const int j1 = tid + 512;
    const int j2 = (tid < 512) ? tid + 1536 : tid - 512;
    h_ext[j1] = hv;
    h_ext[j2] = hv;
  }
  __syncthreads();

  float* xzb = xz + (size_t)b * T_ * H_;
  const float4* wp = reinterpret_cast<const float4*>(&w_lds[kbase]);
  const float4* hp = reinterpret_cast<const float4*>(&h_ext[obase + kbase]);
  const int j1 = tid + 512;
  const int j2 = (tid < 512) ? tid + 1536 : tid - 512;

  for (int t = 0; t < T_; ++t) {
    const float xv = xzb[t * H_ + tid];  // early issue; used after barrier

    float acc[8];
#pragma unroll
    for (int d = 0; d < 8; ++d) acc[d] = 0.f;

    float4 c0 = hp[0], c1 = hp[1];
#pragma unroll
    for (int c = 0; c < 32; ++c) {
      const float4 c2 = hp[c + 2];
      const float4 wv = wp[c];
      const float win[12] = {c0.x, c0.y, c0.z, c0.w, c1.x, c1.y,
                             c1.z, c1.w, c2.x, c2.y, c2.z, c2.w};
      const float wq[4] = {wv.x, wv.y, wv.z, wv.w};
#pragma unroll
      for (int q = 0; q < 4; ++q)
#pragma unroll
        for (int d = 0; d < 8; ++d) acc[d] = fmaf(wq[q], win[q + d], acc[d]);
      c0 = c1;
      c1 = c2;
    }

    float4 p0 = {acc[0], acc[1], acc[2], acc[3]};
    float4 p1 = {acc[4], acc[5], acc[6], acc[7]};
    *(float4*)&partial[g][obase] = p0;
    *(float4*)&partial[g][obase + 4] = p1;
    __syncthreads();

    float s = ((partial[0][tid] + partial[1][tid]) + (partial[2][tid] + partial[3][tid])) +
              ((partial[4][tid] + partial[5][tid]) + (partial[6][tid] + partial[7][tid]));
    const float pre = xv + s;
    const float hn = tanhf(pre);
    xzb[t * H_ + tid] = hn;  // overwrite xp with z (same element this thread read)
    h_ext[j1] = hn;
    h_ext[j2] = hn;
    __syncthreads();
  }
}

// ---------------------------------------------------------------------------
// In-place row softmax over last dim (512), one wave per row.
// ---------------------------------------------------------------------------
__global__ __launch_bounds__(256)
void softmax_rows(float* __restrict__ out, int rows) {
  const int row = blockIdx.x * 4 + (threadIdx.x >> 6);
  if (row >= rows) return;
  const int lane = threadIdx.x & 63;
  float* p = out + (size_t)row * O_;

  float4 v0 = *(float4*)&p[lane * 4];
  float4 v1 = *(float4*)&p[256 + lane * 4];

  float m = fmaxf(fmaxf(fmaxf(v0.x, v0.y), fmaxf(v0.z, v0.w)),
                  fmaxf(fmaxf(v1.x, v1.y), fmaxf(v1.z, v1.w)));
#pragma unroll
  for (int off = 32; off > 0; off >>= 1) m = fmaxf(m, __shfl_xor(m, off));

  v0.x = __expf(v0.x - m);
  v0.y = __expf(v0.y - m);
  v0.z = __expf(v0.z - m);
  v0.w = __expf(v0.w - m);
  v1.x = __expf(v1.x - m);
  v1.y = __expf(v1.y - m);
  v1.z = __expf(v1.z - m);
  v1.w = __expf(v1.w - m);

  float s = ((v0.x + v0.y) + (v0.z + v0.w)) + ((v1.x + v1.y) + (v1.z + v1.w));
#pragma unroll
  for (int off = 32; off > 0; off >>= 1) s += __shfl_xor(s, off);

  const float inv = 1.f / s;
  v0.x *= inv; v0.y *= inv; v0.z *= inv; v0.w *= inv;
  v1.x *= inv; v1.y *= inv; v1.z *= inv; v1.w *= inv;
  *(float4*)&p[lane * 4] = v0;
  *(float4*)&p[256 + lane * 4] = v1;
}

// ---------------------------------------------------------------------------
extern "C" void kernel_launch(void* const* d_in, const int* in_sizes, int n_in,
                              void* d_out, int out_size, void* d_ws, size_t ws_size,
                              hipStream_t stream) {
  const float* x  = (const float*)d_in[0];   // (B,T,N)
  const float* h0 = (const float*)d_in[1];   // (1,B,H)
  const float* Wi = (const float*)d_in[2];   // (H,N)
  const float* bi = (const float*)d_in[3];   // (H,)
  const float* Wo = (const float*)d_in[4];   // (O,H)
  const float* bo = (const float*)d_in[5];   // (O,)
  const float* w  = (const float*)d_in[6];   // (K=H,)

  float* out = (float*)d_out;                      // (B,T,O) softmax
  float* z   = out + (size_t)B_ * T_ * O_;         // (B,T,H) z_seq region

  // Phase 1: x_proj = x @ Wi^T + bi  -> stored into z region (same size)
  gemm_bt_f32<<<dim3((B_ * T_) / 128, H_ / 128), 256, 0, stream>>>(
      x, Wi, bi, z, B_ * T_, H_, N_);

  // Phase 2: recurrence, overwrites xp with z in place
  elman_recurrence<<<B_, 1024, 0, stream>>>(z, h0, w);

  // Phase 3: logits = z @ Wo^T + bo -> out region
  gemm_bt_f32<<<dim3((B_ * T_) / 128, O_ / 128), 256, 0, stream>>>(
      z, Wo, bo, out, B_ * T_, O_, H_);

  // Phase 4: softmax rows in place
  softmax_rows<<<(B_ * T_) / 4, 256, 0, stream>>>(out, B_ * T_);
}

// Round 2
// 3004.914 us; speedup vs baseline: 3.6536x; 3.6536x over previous
//
#include <hip/hip_runtime.h>

#define B_ 32
#define T_ 512
#define N_ 512
#define H_ 1024
#define O_ 512

// ---------------------------------------------------------------------------
// GEMM: C[m,n] = sum_k A[m,k] * Bt[n,k] + bias[n]
// A: M x K row-major, Bt: N x K row-major (both K-contiguous).
// 128x128 tile, BK=16, 256 threads, 8x8 per-thread micro-tile.
// ---------------------------------------------------------------------------
__global__ __launch_bounds__(256)
void gemm_bt_f32(const float* __restrict__ A, const float* __restrict__ Bt,
                 const float* __restrict__ bias, float* __restrict__ C,
                 int M, int N, int K) {
  __shared__ __align__(16) float As[16][128];
  __shared__ __align__(16) float Bs[16][128];
  const int tid = threadIdx.x;
  const int m0 = blockIdx.x * 128;
  const int n0 = blockIdx.y * 128;
  const int tr = tid >> 4;
  const int tc = tid & 15;

  float acc[8][8];
#pragma unroll
  for (int i = 0; i < 8; ++i)
#pragma unroll
    for (int j = 0; j < 8; ++j) acc[i][j] = 0.f;

  for (int k0 = 0; k0 < K; k0 += 16) {
#pragma unroll
    for (int r = 0; r < 2; ++r) {
      const int Q = tid + r * 256;
      const int row = Q >> 2;
      const int kq = Q & 3;
      const float4 av =
          *reinterpret_cast<const float4*>(&A[(size_t)(m0 + row) * K + k0 + kq * 4]);
      As[kq * 4 + 0][row] = av.x;
      As[kq * 4 + 1][row] = av.y;
      As[kq * 4 + 2][row] = av.z;
      As[kq * 4 + 3][row] = av.w;
      const float4 bv =
          *reinterpret_cast<const float4*>(&Bt[(size_t)(n0 + row) * K + k0 + kq * 4]);
      Bs[kq * 4 + 0][row] = bv.x;
      Bs[kq * 4 + 1][row] = bv.y;
      Bs[kq * 4 + 2][row] = bv.z;
      Bs[kq * 4 + 3][row] = bv.w;
    }
    __syncthreads();
#pragma unroll
    for (int kk = 0; kk < 16; ++kk) {
      float a[8], b[8];
      *(float4*)&a[0] = *(const float4*)&As[kk][tr * 8];
      *(float4*)&a[4] = *(const float4*)&As[kk][tr * 8 + 4];
      *(float4*)&b[0] = *(const float4*)&Bs[kk][tc * 8];
      *(float4*)&b[4] = *(const float4*)&Bs[kk][tc * 8 + 4];
#pragma unroll
      for (int i = 0; i < 8; ++i)
#pragma unroll
        for (int j = 0; j < 8; ++j) acc[i][j] = fmaf(a[i], b[j], acc[i][j]);
    }
    __syncthreads();
  }

  float br[8];
#pragma unroll
  for (int j = 0; j < 8; ++j) br[j] = bias[n0 + tc * 8 + j];
#pragma unroll
  for (int i = 0; i < 8; ++i) {
    float4 s0, s1;
    s0.x = acc[i][0] + br[0];
    s0.y = acc[i][1] + br[1];
    s0.z = acc[i][2] + br[2];
    s0.w = acc[i][3] + br[3];
    s1.x = acc[i][4] + br[4];
    s1.y = acc[i][5] + br[5];
    s1.z = acc[i][6] + br[6];
    s1.w = acc[i][7] + br[7];
    float* cp = &C[(size_t)(m0 + tr * 8 + i) * N + n0 + tc * 8];
    *(float4*)cp = s0;
    *(float4*)(cp + 4) = s1;
  }
}

// ---------------------------------------------------------------------------
// Elman recurrence, one block (1024 threads) per batch element.
//
// Decomposition: thread (u = tid>>4, g = tid&15) computes partial sums of
// outputs o = 16u..16u+15 over taps k = 64g..64g+63, with the 64 w-taps held
// in VGPRs (loaded once) and a 20-float sliding register window over h.
// The 16 tap-group partials live in the 16 lanes of an aligned 16-lane
// subgroup -> recursive-halving __shfl_xor reduce (no LDS partials); lane g
// ends holding output 16u+g == tid -> coalesced global stores.
//
// h is double-buffered in LDS as h_ext[j] = h[(j-512) mod 1024], j in
// [0,2048), stored XOR-swizzled at float4 granularity: sigma(q)=q^((q>>3)&7).
// Raw read pattern (f4 idx = 4u+16g+c) has all lanes on 2 bank-columns
// (16g%8==0); sigma spreads every bank-column across exactly 8 lanes = the
// conflict-free minimum for ds_read_b128. One __syncthreads per step.
// ---------------------------------------------------------------------------
__device__ __forceinline__ int swz(int q) { return q ^ ((q >> 3) & 7); }

__global__ __launch_bounds__(1024)
void elman_recurrence(float* __restrict__ xz, const float* __restrict__ h0,
                      const float* __restrict__ w) {
  __shared__ __align__(16) float hb[2][2048];

  const int b = blockIdx.x;
  const int tid = threadIdx.x;
  const int u = tid >> 4;  // 0..63  -> outputs 16u..16u+15
  const int g = tid & 15;  // 0..15  -> taps 64g..64g+63

  // w taps for this lane's k-range -> registers (64 floats)
  float4 wr[16];
  {
    const float4* wp = reinterpret_cast<const float4*>(w + (g << 6));
#pragma unroll
    for (int i = 0; i < 16; ++i) wr[i] = wp[i];
  }

  // swizzled physical float offsets for this thread's two h_ext copies
  const int j1 = tid + 512;
  const int j2 = (tid < 512) ? tid + 1536 : tid - 512;
  const int o1 = (swz(j1 >> 2) << 2) | (j1 & 3);
  const int o2 = (swz(j2 >> 2) << 2) | (j2 & 3);

  hb[0][o1] = h0[b * H_ + tid];
  hb[0][o2] = hb[0][o1];
  __syncthreads();

  float* xzb = xz + (size_t)b * T_ * H_;
  const int Q0 = (u << 2) + (g << 4);  // f4 index of window start (j = 16u+64g)

  int pp = 0;
  for (int t = 0; t < T_; ++t) {
    const float xv = xzb[t * H_ + tid];  // issued early, used after tap loop
    const float* rd = hb[pp];

    float acc[16];
#pragma unroll
    for (int d = 0; d < 16; ++d) acc[d] = 0.f;

    // sliding 20-float window, fully unrolled (all indices static)
    float win[20];
#pragma unroll
    for (int c = 0; c < 5; ++c) {
      const float4 f = *reinterpret_cast<const float4*>(rd + (swz(Q0 + c) << 2));
      win[4 * c + 0] = f.x;
      win[4 * c + 1] = f.y;
      win[4 * c + 2] = f.z;
      win[4 * c + 3] = f.w;
    }
#pragma unroll
    for (int c = 0; c < 16; ++c) {
      float4 nf = {0.f, 0.f, 0.f, 0.f};
      if (c < 15)
        nf = *reinterpret_cast<const float4*>(rd + (swz(Q0 + 5 + c) << 2));
      const float wq0 = wr[c].x, wq1 = wr[c].y, wq2 = wr[c].z, wq3 = wr[c].w;
#pragma unroll
      for (int d = 0; d < 16; ++d) {
        acc[d] = fmaf(wq0, win[0 + d], acc[d]);
        acc[d] = fmaf(wq1, win[1 + d], acc[d]);
        acc[d] = fmaf(wq2, win[2 + d], acc[d]);
        acc[d] = fmaf(wq3, win[3 + d], acc[d]);
      }
      if (c < 15) {
#pragma unroll
        for (int i = 0; i < 16; ++i) win[i] = win[i + 4];
        win[16] = nf.x;
        win[17] = nf.y;
        win[18] = nf.z;
        win[19] = nf.w;
      }
    }

    // recursive-halving reduce across the 16 g-lanes (masks 1,2,4,8 stay
    // inside the aligned 16-lane subgroup). After round matching bit b of
    // the output index with bit b of g, lane g holds output 16u+g.
    float v8[8];
#pragma unroll
    for (int d = 0; d < 8; ++d) {
      const float keep = (g & 1) ? acc[2 * d + 1] : acc[2 * d];
      const float send = (g & 1) ? acc[2 * d] : acc[2 * d + 1];
      v8[d] = keep + __shfl_xor(send, 1);
    }
    float v4[4];
#pragma unroll
    for (int d = 0; d < 4; ++d) {
      const float keep = ((g >> 1) & 1) ? v8[2 * d + 1] : v8[2 * d];
      const float send = ((g >> 1) & 1) ? v8[2 * d] : v8[2 * d + 1];
      v4[d] = keep + __shfl_xor(send, 2);
    }
    float v2[2];
#pragma unroll
    for (int d = 0; d < 2; ++d) {
      const float keep = ((g >> 2) & 1) ? v4[2 * d + 1] : v4[2 * d];
      const float send = ((g >> 2) & 1) ? v4[2 * d] : v4[2 * d + 1];
      v2[d] = keep + __shfl_xor(send, 4);
    }
    float y;
    {
      const float keep = ((g >> 3) & 1) ? v2[1] : v2[0];
      const float send = ((g >> 3) & 1) ? v2[0] : v2[1];
      y = keep + __shfl_xor(send, 8);
    }

    const float hn = tanhf(xv + y);
    xzb[t * H_ + tid] = hn;  // overwrite x_proj with z (same element)
    float* wrb = hb[pp ^ 1];
    wrb[o1] = hn;
    wrb[o2] = hn;
    pp ^= 1;
    __syncthreads();  // writes to new buffer visible; old buffer free
  }
}

// ---------------------------------------------------------------------------
// In-place row softmax over last dim (512), one wave per row.
// ---------------------------------------------------------------------------
__global__ __launch_bounds__(256)
void softmax_rows(float* __restrict__ out, int rows) {
  const int row = blockIdx.x * 4 + (threadIdx.x >> 6);
  if (row >= rows) return;
  const int lane = threadIdx.x & 63;
  float* p = out + (size_t)row * O_;

  float4 v0 = *(float4*)&p[lane * 4];
  float4 v1 = *(float4*)&p[256 + lane * 4];

  float m = fmaxf(fmaxf(fmaxf(v0.x, v0.y), fmaxf(v0.z, v0.w)),
                  fmaxf(fmaxf(v1.x, v1.y), fmaxf(v1.z, v1.w)));
#pragma unroll
  for (int off = 32; off > 0; off >>= 1) m = fmaxf(m, __shfl_xor(m, off));

  v0.x = __expf(v0.x - m);
  v0.y = __expf(v0.y - m);
  v0.z = __expf(v0.z - m);
  v0.w = __expf(v0.w - m);
  v1.x = __expf(v1.x - m);
  v1.y = __expf(v1.y - m);
  v1.z = __expf(v1.z - m);
  v1.w = __expf(v1.w - m);

  float s = ((v0.x + v0.y) + (v0.z + v0.w)) + ((v1.x + v1.y) + (v1.z + v1.w));
#pragma unroll
  for (int off = 32; off > 0; off >>= 1) s += __shfl_xor(s, off);

  const float inv = 1.f / s;
  v0.x *= inv; v0.y *= inv; v0.z *= inv; v0.w *= inv;
  v1.x *= inv; v1.y *= inv; v1.z *= inv; v1.w *= inv;
  *(float4*)&p[lane * 4] = v0;
  *(float4*)&p[256 + lane * 4] = v1;
}

// ---------------------------------------------------------------------------
extern "C" void kernel_launch(void* const* d_in, const int* in_sizes, int n_in,
                              void* d_out, int out_size, void* d_ws, size_t ws_size,
                              hipStream_t stream) {
  const float* x  = (const float*)d_in[0];   // (B,T,N)
  const float* h0 = (const float*)d_in[1];   // (1,B,H)
  const float* Wi = (const float*)d_in[2];   // (H,N)
  const float* bi = (const float*)d_in[3];   // (H,)
  const float* Wo = (const float*)d_in[4];   // (O,H)
  const float* bo = (const float*)d_in[5];   // (O,)
  const float* w  = (const float*)d_in[6];   // (K=H,)

  float* out = (float*)d_out;                      // (B,T,O) softmax
  float* z   = out + (size_t)B_ * T_ * O_;         // (B,T,H) z_seq region

  // Phase 1: x_proj = x @ Wi^T + bi  -> stored into z region (same size)
  gemm_bt_f32<<<dim3((B_ * T_) / 128, H_ / 128), 256, 0, stream>>>(
      x, Wi, bi, z, B_ * T_, H_, N_);

  // Phase 2: recurrence, overwrites xp with z in place
  elman_recurrence<<<B_, 1024, 0, stream>>>(z, h0, w);

  // Phase 3: logits = z @ Wo^T + bo -> out region
  gemm_bt_f32<<<dim3((B_ * T_) / 128, O_ / 128), 256, 0, stream>>>(
      z, Wo, bo, out, B_ * T_, O_, H_);

  // Phase 4: softmax rows in place
  softmax_rows<<<(B_ * T_) / 4, 256, 0, stream>>>(out, B_ * T_);
}

// Round 3
// 2867.144 us; speedup vs baseline: 3.8291x; 1.0481x over previous
//
#include <hip/hip_runtime.h>

#define B_ 32
#define T_ 512
#define N_ 512
#define H_ 1024
#define O_ 512

typedef _Float16 h2 __attribute__((ext_vector_type(2)));
typedef _Float16 h8 __attribute__((ext_vector_type(8)));

__device__ __forceinline__ float fdot2(h2 a, h2 b, float c) {
#if defined(__has_builtin) && __has_builtin(__builtin_amdgcn_fdot2)
  return __builtin_amdgcn_fdot2(a, b, c, false);
#else
  float d;
  asm("v_dot2_f32_f16 %0, %1, %2, %3" : "=v"(d) : "v"(a), "v"(b), "v"(c));
  return d;
#endif
}

// ---------------------------------------------------------------------------
// GEMM: C[m,n] = sum_k A[m,k] * Bt[n,k] + bias[n]
// A: M x K row-major, Bt: N x K row-major (both K-contiguous).
// 128x128 tile, BK=16, 256 threads, 8x8 per-thread micro-tile.
// ---------------------------------------------------------------------------
__global__ __launch_bounds__(256)
void gemm_bt_f32(const float* __restrict__ A, const float* __restrict__ Bt,
                 const float* __restrict__ bias, float* __restrict__ C,
                 int M, int N, int K) {
  __shared__ __align__(16) float As[16][128];
  __shared__ __align__(16) float Bs[16][128];
  const int tid = threadIdx.x;
  const int m0 = blockIdx.x * 128;
  const int n0 = blockIdx.y * 128;
  const int tr = tid >> 4;
  const int tc = tid & 15;

  float acc[8][8];
#pragma unroll
  for (int i = 0; i < 8; ++i)
#pragma unroll
    for (int j = 0; j < 8; ++j) acc[i][j] = 0.f;

  for (int k0 = 0; k0 < K; k0 += 16) {
#pragma unroll
    for (int r = 0; r < 2; ++r) {
      const int Q = tid + r * 256;
      const int row = Q >> 2;
      const int kq = Q & 3;
      const float4 av =
          *reinterpret_cast<const float4*>(&A[(size_t)(m0 + row) * K + k0 + kq * 4]);
      As[kq * 4 + 0][row] = av.x;
      As[kq * 4 + 1][row] = av.y;
      As[kq * 4 + 2][row] = av.z;
      As[kq * 4 + 3][row] = av.w;
      const float4 bv =
          *reinterpret_cast<const float4*>(&Bt[(size_t)(n0 + row) * K + k0 + kq * 4]);
      Bs[kq * 4 + 0][row] = bv.x;
      Bs[kq * 4 + 1][row] = bv.y;
      Bs[kq * 4 + 2][row] = bv.z;
      Bs[kq * 4 + 3][row] = bv.w;
    }
    __syncthreads();
#pragma unroll
    for (int kk = 0; kk < 16; ++kk) {
      float a[8], b[8];
      *(float4*)&a[0] = *(const float4*)&As[kk][tr * 8];
      *(float4*)&a[4] = *(const float4*)&As[kk][tr * 8 + 4];
      *(float4*)&b[0] = *(const float4*)&Bs[kk][tc * 8];
      *(float4*)&b[4] = *(const float4*)&Bs[kk][tc * 8 + 4];
#pragma unroll
      for (int i = 0; i < 8; ++i)
#pragma unroll
        for (int j = 0; j < 8; ++j) acc[i][j] = fmaf(a[i], b[j], acc[i][j]);
    }
    __syncthreads();
  }

  float br[8];
#pragma unroll
  for (int j = 0; j < 8; ++j) br[j] = bias[n0 + tc * 8 + j];
#pragma unroll
  for (int i = 0; i < 8; ++i) {
    float4 s0, s1;
    s0.x = acc[i][0] + br[0];
    s0.y = acc[i][1] + br[1];
    s0.z = acc[i][2] + br[2];
    s0.w = acc[i][3] + br[3];
    s1.x = acc[i][4] + br[4];
    s1.y = acc[i][5] + br[5];
    s1.z = acc[i][6] + br[6];
    s1.w = acc[i][7] + br[7];
    float* cp = &C[(size_t)(m0 + tr * 8 + i) * N + n0 + tc * 8];
    *(float4*)cp = s0;
    *(float4*)(cp + 4) = s1;
  }
}

// ---------------------------------------------------------------------------
// Elman recurrence, one block (1024 threads) per batch element, f16 dot2.
//
// Thread (u = tid>>4, g = tid&15): outputs o = 16u+d (d=0..15), taps
// k = 64g..64g+63. Inner product uses v_dot2_f32_f16 (2 f16 MAC/instr,
// f32 accumulate) -> 512 dot2/step instead of 1024 f32 FMA.
//
// Alignment trick: h kept in LDS twice as f16 —
//   A[j] = h_ext[j]   (aligned pairs  (h[2m],h[2m+1]))
//   S[j] = h_ext[j+1] (shifted pairs  (h[2m+1],h[2m+2]))
// Even outputs d=2e:  acc += dot2(wA[p], Apair[e+p])
// Odd  outputs d=2e+1: acc += dot2(wA[p], Spair[e+p])
// -> every dot2 operand is a naturally-aligned half2; no repacking.
// w taps held in VGPRs as 32 aligned half2.
//
// XOR quad-swizzle sigma(Q)=Q^((Q>>3)&7) on 16B quads (8 f16) keeps the
// strided window ds_read_b128 conflict-free. Double-buffered h, one
// __syncthreads per step. Partials reduced across the 16 g-lanes with
// recursive-halving __shfl_xor; lane g ends holding output 16u+g == tid.
// ---------------------------------------------------------------------------
__device__ __forceinline__ int swzq(int q) { return q ^ ((q >> 3) & 7); }
__device__ __forceinline__ int pelem(int e) {
  return (swzq(e >> 3) << 3) | (e & 7);
}

__global__ __launch_bounds__(1024)
void elman_recurrence(float* __restrict__ xz, const float* __restrict__ h0,
                      const float* __restrict__ w) {
  __shared__ __align__(16) _Float16 Ab[2][2048];
  __shared__ __align__(16) _Float16 Sb[2][2048];

  const int b = blockIdx.x;
  const int tid = threadIdx.x;
  const int u = tid >> 4;  // 0..63 -> outputs 16u..16u+15
  const int g = tid & 15;  // 0..15 -> taps 64g..64g+63

  // w taps -> 32 aligned half2 in VGPRs
  h2 wA[32];
  {
    const float* wg = w + (g << 6);
#pragma unroll
    for (int p = 0; p < 32; ++p) {
      h2 t;
      t.x = (_Float16)wg[2 * p];
      t.y = (_Float16)wg[2 * p + 1];
      wA[p] = t;
    }
  }

  // h_ext positions for this thread's value (duplicated for circularity)
  const int j1 = tid + 512;
  const int j2 = (tid < 512) ? tid + 1536 : tid - 512;
  const int pa1 = pelem(j1), pa2 = pelem(j2);
  const int ps1 = pelem(j1 - 1);                       // j1-1 >= 511, safe
  const int ps2 = (tid != 512) ? pelem(j2 - 1) : -1;   // skip S[-1]

  {
    const _Float16 hh = (_Float16)h0[b * H_ + tid];
    Ab[0][pa1] = hh;
    Ab[0][pa2] = hh;
    Sb[0][ps1] = hh;
    if (ps2 >= 0) Sb[0][ps2] = hh;
  }
  __syncthreads();

  float* xzb = xz + (size_t)b * T_ * H_;
  const int q0 = 2 * u + 8 * g;  // first 16B quad of window (J=16u+64g, J>>3)

  int pp = 0;
  for (int t = 0; t < T_; ++t) {
    const float xv = xzb[t * H_ + tid];  // issued early, used after dot loop
    const _Float16* Ar = Ab[pp];
    const _Float16* Sr = Sb[pp];

    float acc[16];
#pragma unroll
    for (int d = 0; d < 16; ++d) acc[d] = 0.f;

    // phase 1: even outputs from aligned-pair window
    {
      h2 W[40];
#pragma unroll
      for (int c = 0; c < 10; ++c) {
        const h8 qv = *reinterpret_cast<const h8*>(Ar + (swzq(q0 + c) << 3));
        W[4 * c + 0] = __builtin_shufflevector(qv, qv, 0, 1);
        W[4 * c + 1] = __builtin_shufflevector(qv, qv, 2, 3);
        W[4 * c + 2] = __builtin_shufflevector(qv, qv, 4, 5);
        W[4 * c + 3] = __builtin_shufflevector(qv, qv, 6, 7);
      }
#pragma unroll
      for (int p = 0; p < 32; ++p)
#pragma unroll
        for (int e = 0; e < 8; ++e)
          acc[2 * e] = fdot2(wA[p], W[e + p], acc[2 * e]);
    }

    // phase 2: odd outputs from shifted-pair window
    {
      h2 W[40];
#pragma unroll
      for (int c = 0; c < 10; ++c) {
        const h8 qv = *reinterpret_cast<const h8*>(Sr + (swzq(q0 + c) << 3));
        W[4 * c + 0] = __builtin_shufflevector(qv, qv, 0, 1);
        W[4 * c + 1] = __builtin_shufflevector(qv, qv, 2, 3);
        W[4 * c + 2] = __builtin_shufflevector(qv, qv, 4, 5);
        W[4 * c + 3] = __builtin_shufflevector(qv, qv, 6, 7);
      }
#pragma unroll
      for (int p = 0; p < 32; ++p)
#pragma unroll
        for (int e = 0; e < 8; ++e)
          acc[2 * e + 1] = fdot2(wA[p], W[e + p], acc[2 * e + 1]);
    }

    // recursive-halving reduce across the 16 g-lanes; lane g ends with
    // output 16u+g == tid.
    float v8[8];
#pragma unroll
    for (int d = 0; d < 8; ++d) {
      const float keep = (g & 1) ? acc[2 * d + 1] : acc[2 * d];
      const float send = (g & 1) ? acc[2 * d] : acc[2 * d + 1];
      v8[d] = keep + __shfl_xor(send, 1);
    }
    float v4[4];
#pragma unroll
    for (int d = 0; d < 4; ++d) {
      const float keep = ((g >> 1) & 1) ? v8[2 * d + 1] : v8[2 * d];
      const float send = ((g >> 1) & 1) ? v8[2 * d] : v8[2 * d + 1];
      v4[d] = keep + __shfl_xor(send, 2);
    }
    float v2[2];
#pragma unroll
    for (int d = 0; d < 2; ++d) {
      const float keep = ((g >> 2) & 1) ? v4[2 * d + 1] : v4[2 * d];
      const float send = ((g >> 2) & 1) ? v4[2 * d] : v4[2 * d + 1];
      v2[d] = keep + __shfl_xor(send, 4);
    }
    float y;
    {
      const float keep = ((g >> 3) & 1) ? v2[1] : v2[0];
      const float send = ((g >> 3) & 1) ? v2[0] : v2[1];
      y = keep + __shfl_xor(send, 8);
    }

    const float hn = tanhf(xv + y);
    xzb[t * H_ + tid] = hn;  // overwrite x_proj with z (same element)
    const _Float16 hf = (_Float16)hn;
    _Float16* An = Ab[pp ^ 1];
    _Float16* Sn = Sb[pp ^ 1];
    An[pa1] = hf;
    An[pa2] = hf;
    Sn[ps1] = hf;
    if (ps2 >= 0) Sn[ps2] = hf;
    pp ^= 1;
    __syncthreads();
  }
}

// ---------------------------------------------------------------------------
// In-place row softmax over last dim (512), one wave per row.
// ---------------------------------------------------------------------------
__global__ __launch_bounds__(256)
void softmax_rows(float* __restrict__ out, int rows) {
  const int row = blockIdx.x * 4 + (threadIdx.x >> 6);
  if (row >= rows) return;
  const int lane = threadIdx.x & 63;
  float* p = out + (size_t)row * O_;

  float4 v0 = *(float4*)&p[lane * 4];
  float4 v1 = *(float4*)&p[256 + lane * 4];

  float m = fmaxf(fmaxf(fmaxf(v0.x, v0.y), fmaxf(v0.z, v0.w)),
                  fmaxf(fmaxf(v1.x, v1.y), fmaxf(v1.z, v1.w)));
#pragma unroll
  for (int off = 32; off > 0; off >>= 1) m = fmaxf(m, __shfl_xor(m, off));

  v0.x = __expf(v0.x - m);
  v0.y = __expf(v0.y - m);
  v0.z = __expf(v0.z - m);
  v0.w = __expf(v0.w - m);
  v1.x = __expf(v1.x - m);
  v1.y = __expf(v1.y - m);
  v1.z = __expf(v1.z - m);
  v1.w = __expf(v1.w - m);

  float s = ((v0.x + v0.y) + (v0.z + v0.w)) + ((v1.x + v1.y) + (v1.z + v1.w));
#pragma unroll
  for (int off = 32; off > 0; off >>= 1) s += __shfl_xor(s, off);

  const float inv = 1.f / s;
  v0.x *= inv; v0.y *= inv; v0.z *= inv; v0.w *= inv;
  v1.x *= inv; v1.y *= inv; v1.z *= inv; v1.w *= inv;
  *(float4*)&p[lane * 4] = v0;
  *(float4*)&p[256 + lane * 4] = v1;
}

// ---------------------------------------------------------------------------
extern "C" void kernel_launch(void* const* d_in, const int* in_sizes, int n_in,
                              void* d_out, int out_size, void* d_ws, size_t ws_size,
                              hipStream_t stream) {
  const float* x  = (const float*)d_in[0];   // (B,T,N)
  const float* h0 = (const float*)d_in[1];   // (1,B,H)
  const float* Wi = (const float*)d_in[2];   // (H,N)
  const float* bi = (const float*)d_in[3];   // (H,)
  const float* Wo = (const float*)d_in[4];   // (O,H)
  const float* bo = (const float*)d_in[5];   // (O,)
  const float* w  = (const float*)d_in[6];   // (K=H,)

  float* out = (float*)d_out;                      // (B,T,O) softmax
  float* z   = out + (size_t)B_ * T_ * O_;         // (B,T,H) z_seq region

  // Phase 1: x_proj = x @ Wi^T + bi  -> stored into z region (same size)
  gemm_bt_f32<<<dim3((B_ * T_) / 128, H_ / 128), 256, 0, stream>>>(
      x, Wi, bi, z, B_ * T_, H_, N_);

  // Phase 2: recurrence, overwrites xp with z in place
  elman_recurrence<<<B_, 1024, 0, stream>>>(z, h0, w);

  // Phase 3: logits = z @ Wo^T + bo -> out region
  gemm_bt_f32<<<dim3((B_ * T_) / 128, O_ / 128), 256, 0, stream>>>(
      z, Wo, bo, out, B_ * T_, O_, H_);

  // Phase 4: softmax rows in place
  softmax_rows<<<(B_ * T_) / 4, 256, 0, stream>>>(out, B_ * T_);
}

// Round 4
// 2845.020 us; speedup vs baseline: 3.8589x; 1.0078x over previous
//
#include <hip/hip_runtime.h>

#define B_ 32
#define T_ 512
#define N_ 512
#define H_ 1024
#define O_ 512

typedef _Float16 h2 __attribute__((ext_vector_type(2)));
typedef _Float16 h8 __attribute__((ext_vector_type(8)));

__device__ __forceinline__ float fdot2(h2 a, h2 b, float c) {
#if defined(__has_builtin) && __has_builtin(__builtin_amdgcn_fdot2)
  return __builtin_amdgcn_fdot2(a, b, c, false);
#else
  float d;
  asm("v_dot2_f32_f16 %0, %1, %2, %3" : "=v"(d) : "v"(a), "v"(b), "v"(c));
  return d;
#endif
}

// branch-free tanh: 1 - 2/(exp(2x)+1). Correct limits: x->+inf -> 1,
// x->-inf -> -1 (exp->0). ~6 instrs vs libm's ~25.
__device__ __forceinline__ float tanh_fast(float x) {
  return 1.f - 2.f / (__expf(2.f * x) + 1.f);
}

// ---------------------------------------------------------------------------
// GEMM: C[m,n] = sum_k A[m,k] * Bt[n,k] + bias[n]
// A: M x K row-major, Bt: N x K row-major (both K-contiguous).
// 128x128 tile, BK=16, 256 threads, 8x8 per-thread micro-tile.
// ---------------------------------------------------------------------------
__global__ __launch_bounds__(256)
void gemm_bt_f32(const float* __restrict__ A, const float* __restrict__ Bt,
                 const float* __restrict__ bias, float* __restrict__ C,
                 int M, int N, int K) {
  __shared__ __align__(16) float As[16][128];
  __shared__ __align__(16) float Bs[16][128];
  const int tid = threadIdx.x;
  const int m0 = blockIdx.x * 128;
  const int n0 = blockIdx.y * 128;
  const int tr = tid >> 4;
  const int tc = tid & 15;

  float acc[8][8];
#pragma unroll
  for (int i = 0; i < 8; ++i)
#pragma unroll
    for (int j = 0; j < 8; ++j) acc[i][j] = 0.f;

  for (int k0 = 0; k0 < K; k0 += 16) {
#pragma unroll
    for (int r = 0; r < 2; ++r) {
      const int Q = tid + r * 256;
      const int row = Q >> 2;
      const int kq = Q & 3;
      const float4 av =
          *reinterpret_cast<const float4*>(&A[(size_t)(m0 + row) * K + k0 + kq * 4]);
      As[kq * 4 + 0][row] = av.x;
      As[kq * 4 + 1][row] = av.y;
      As[kq * 4 + 2][row] = av.z;
      As[kq * 4 + 3][row] = av.w;
      const float4 bv =
          *reinterpret_cast<const float4*>(&Bt[(size_t)(n0 + row) * K + k0 + kq * 4]);
      Bs[kq * 4 + 0][row] = bv.x;
      Bs[kq * 4 + 1][row] = bv.y;
      Bs[kq * 4 + 2][row] = bv.z;
      Bs[kq * 4 + 3][row] = bv.w;
    }
    __syncthreads();
#pragma unroll
    for (int kk = 0; kk < 16; ++kk) {
      float a[8], b[8];
      *(float4*)&a[0] = *(const float4*)&As[kk][tr * 8];
      *(float4*)&a[4] = *(const float4*)&As[kk][tr * 8 + 4];
      *(float4*)&b[0] = *(const float4*)&Bs[kk][tc * 8];
      *(float4*)&b[4] = *(const float4*)&Bs[kk][tc * 8 + 4];
#pragma unroll
      for (int i = 0; i < 8; ++i)
#pragma unroll
        for (int j = 0; j < 8; ++j) acc[i][j] = fmaf(a[i], b[j], acc[i][j]);
    }
    __syncthreads();
  }

  float br[8];
#pragma unroll
  for (int j = 0; j < 8; ++j) br[j] = bias[n0 + tc * 8 + j];
#pragma unroll
  for (int i = 0; i < 8; ++i) {
    float4 s0, s1;
    s0.x = acc[i][0] + br[0];
    s0.y = acc[i][1] + br[1];
    s0.z = acc[i][2] + br[2];
    s0.w = acc[i][3] + br[3];
    s1.x = acc[i][4] + br[4];
    s1.y = acc[i][5] + br[5];
    s1.z = acc[i][6] + br[6];
    s1.w = acc[i][7] + br[7];
    float* cp = &C[(size_t)(m0 + tr * 8 + i) * N + n0 + tc * 8];
    *(float4*)cp = s0;
    *(float4*)(cp + 4) = s1;
  }
}

// ---------------------------------------------------------------------------
// Elman recurrence, one block (1024 threads) per batch element, f16 dot2.
//
// Thread (u = tid>>4, g = tid&15): outputs o = 16u+d (d=0..15), taps
// k = 64g..64g+63. v_dot2_f32_f16 (2 f16 MAC, f32 accumulate).
//
// h kept in LDS twice as f16: A[j] = h_ext[j] (aligned pairs), S[j] =
// h_ext[j+1] (shifted pairs). Even outputs use A-window, odd outputs use
// S-window -> every dot2 operand naturally aligned, no repacking. w taps
// in VGPRs as 32 aligned half2.
//
// __launch_bounds__(1024, 4): 16 waves = 1 block/CU = 4 waves/EU -> grants
// the full 128-VGPR budget so wA[32]+W[40]+acc[16] stay in VGPRs (default
// heuristic capped at 44 VGPRs -> AGPR ping-pong per dot2 operand).
//
// XOR quad-swizzle sigma(Q)=Q^((Q>>3)&7) on 16B quads keeps ds_read_b128
// conflict-free. Double-buffered h, one __syncthreads per step.
// ---------------------------------------------------------------------------
__device__ __forceinline__ int swzq(int q) { return q ^ ((q >> 3) & 7); }
__device__ __forceinline__ int pelem(int e) {
  return (swzq(e >> 3) << 3) | (e & 7);
}

__global__ __launch_bounds__(1024, 4)
void elman_recurrence(float* __restrict__ xz, const float* __restrict__ h0,
                      const float* __restrict__ w) {
  __shared__ __align__(16) _Float16 Ab[2][2048];
  __shared__ __align__(16) _Float16 Sb[2][2048];

  const int b = blockIdx.x;
  const int tid = threadIdx.x;
  const int u = tid >> 4;  // 0..63 -> outputs 16u..16u+15
  const int g = tid & 15;  // 0..15 -> taps 64g..64g+63

  // w taps -> 32 aligned half2 in VGPRs
  h2 wA[32];
  {
    const float* wg = w + (g << 6);
#pragma unroll
    for (int p = 0; p < 32; ++p) {
      h2 t;
      t.x = (_Float16)wg[2 * p];
      t.y = (_Float16)wg[2 * p + 1];
      wA[p] = t;
    }
  }

  // h_ext positions for this thread's value (duplicated for circularity)
  const int j1 = tid + 512;
  const int j2 = (tid < 512) ? tid + 1536 : tid - 512;
  const int pa1 = pelem(j1), pa2 = pelem(j2);
  const int ps1 = pelem(j1 - 1);                       // j1-1 >= 511, safe
  const int ps2 = (tid != 512) ? pelem(j2 - 1) : -1;   // skip S[-1]

  {
    const _Float16 hh = (_Float16)h0[b * H_ + tid];
    Ab[0][pa1] = hh;
    Ab[0][pa2] = hh;
    Sb[0][ps1] = hh;
    if (ps2 >= 0) Sb[0][ps2] = hh;
  }
  __syncthreads();

  float* xzb = xz + (size_t)b * T_ * H_;
  const int q0 = 2 * u + 8 * g;  // first 16B quad of window (J=16u+64g, J>>3)

  int pp = 0;
  for (int t = 0; t < T_; ++t) {
    const float xv = xzb[t * H_ + tid];  // issued early, used after dot loop
    const _Float16* Ar = Ab[pp];
    const _Float16* Sr = Sb[pp];

    float acc[16];
#pragma unroll
    for (int d = 0; d < 16; ++d) acc[d] = 0.f;

    // phase 1: even outputs from aligned-pair window
    {
      h2 W[40];
#pragma unroll
      for (int c = 0; c < 10; ++c) {
        const h8 qv = *reinterpret_cast<const h8*>(Ar + (swzq(q0 + c) << 3));
        W[4 * c + 0] = __builtin_shufflevector(qv, qv, 0, 1);
        W[4 * c + 1] = __builtin_shufflevector(qv, qv, 2, 3);
        W[4 * c + 2] = __builtin_shufflevector(qv, qv, 4, 5);
        W[4 * c + 3] = __builtin_shufflevector(qv, qv, 6, 7);
      }
#pragma unroll
      for (int p = 0; p < 32; ++p)
#pragma unroll
        for (int e = 0; e < 8; ++e)
          acc[2 * e] = fdot2(wA[p], W[e + p], acc[2 * e]);
    }

    // phase 2: odd outputs from shifted-pair window
    {
      h2 W[40];
#pragma unroll
      for (int c = 0; c < 10; ++c) {
        const h8 qv = *reinterpret_cast<const h8*>(Sr + (swzq(q0 + c) << 3));
        W[4 * c + 0] = __builtin_shufflevector(qv, qv, 0, 1);
        W[4 * c + 1] = __builtin_shufflevector(qv, qv, 2, 3);
        W[4 * c + 2] = __builtin_shufflevector(qv, qv, 4, 5);
        W[4 * c + 3] = __builtin_shufflevector(qv, qv, 6, 7);
      }
#pragma unroll
      for (int p = 0; p < 32; ++p)
#pragma unroll
        for (int e = 0; e < 8; ++e)
          acc[2 * e + 1] = fdot2(wA[p], W[e + p], acc[2 * e + 1]);
    }

    // recursive-halving reduce across the 16 g-lanes; lane g ends with
    // output 16u+g == tid.
    float v8[8];
#pragma unroll
    for (int d = 0; d < 8; ++d) {
      const float keep = (g & 1) ? acc[2 * d + 1] : acc[2 * d];
      const float send = (g & 1) ? acc[2 * d] : acc[2 * d + 1];
      v8[d] = keep + __shfl_xor(send, 1);
    }
    float v4[4];
#pragma unroll
    for (int d = 0; d < 4; ++d) {
      const float keep = ((g >> 1) & 1) ? v8[2 * d + 1] : v8[2 * d];
      const float send = ((g >> 1) & 1) ? v8[2 * d] : v8[2 * d + 1];
      v4[d] = keep + __shfl_xor(send, 2);
    }
    float v2[2];
#pragma unroll
    for (int d = 0; d < 2; ++d) {
      const float keep = ((g >> 2) & 1) ? v4[2 * d + 1] : v4[2 * d];
      const float send = ((g >> 2) & 1) ? v4[2 * d] : v4[2 * d + 1];
      v2[d] = keep + __shfl_xor(send, 4);
    }
    float y;
    {
      const float keep = ((g >> 3) & 1) ? v2[1] : v2[0];
      const float send = ((g >> 3) & 1) ? v2[0] : v2[1];
      y = keep + __shfl_xor(send, 8);
    }

    const float hn = tanh_fast(xv + y);
    xzb[t * H_ + tid] = hn;  // overwrite x_proj with z (same element)
    const _Float16 hf = (_Float16)hn;
    _Float16* An = Ab[pp ^ 1];
    _Float16* Sn = Sb[pp ^ 1];
    An[pa1] = hf;
    An[pa2] = hf;
    Sn[ps1] = hf;
    if (ps2 >= 0) Sn[ps2] = hf;
    pp ^= 1;
    __syncthreads();
  }
}

// ---------------------------------------------------------------------------
// In-place row softmax over last dim (512), one wave per row.
// ---------------------------------------------------------------------------
__global__ __launch_bounds__(256)
void softmax_rows(float* __restrict__ out, int rows) {
  const int row = blockIdx.x * 4 + (threadIdx.x >> 6);
  if (row >= rows) return;
  const int lane = threadIdx.x & 63;
  float* p = out + (size_t)row * O_;

  float4 v0 = *(float4*)&p[lane * 4];
  float4 v1 = *(float4*)&p[256 + lane * 4];

  float m = fmaxf(fmaxf(fmaxf(v0.x, v0.y), fmaxf(v0.z, v0.w)),
                  fmaxf(fmaxf(v1.x, v1.y), fmaxf(v1.z, v1.w)));
#pragma unroll
  for (int off = 32; off > 0; off >>= 1) m = fmaxf(m, __shfl_xor(m, off));

  v0.x = __expf(v0.x - m);
  v0.y = __expf(v0.y - m);
  v0.z = __expf(v0.z - m);
  v0.w = __expf(v0.w - m);
  v1.x = __expf(v1.x - m);
  v1.y = __expf(v1.y - m);
  v1.z = __expf(v1.z - m);
  v1.w = __expf(v1.w - m);

  float s = ((v0.x + v0.y) + (v0.z + v0.w)) + ((v1.x + v1.y) + (v1.z + v1.w));
#pragma unroll
  for (int off = 32; off > 0; off >>= 1) s += __shfl_xor(s, off);

  const float inv = 1.f / s;
  v0.x *= inv; v0.y *= inv; v0.z *= inv; v0.w *= inv;
  v1.x *= inv; v1.y *= inv; v1.z *= inv; v1.w *= inv;
  *(float4*)&p[lane * 4] = v0;
  *(float4*)&p[256 + lane * 4] = v1;
}

// ---------------------------------------------------------------------------
extern "C" void kernel_launch(void* const* d_in, const int* in_sizes, int n_in,
                              void* d_out, int out_size, void* d_ws, size_t ws_size,
                              hipStream_t stream) {
  const float* x  = (const float*)d_in[0];   // (B,T,N)
  const float* h0 = (const float*)d_in[1];   // (1,B,H)
  const float* Wi = (const float*)d_in[2];   // (H,N)
  const float* bi = (const float*)d_in[3];   // (H,)
  const float* Wo = (const float*)d_in[4];   // (O,H)
  const float* bo = (const float*)d_in[5];   // (O,)
  const float* w  = (const float*)d_in[6];   // (K=H,)

  float* out = (float*)d_out;                      // (B,T,O) softmax
  float* z   = out + (size_t)B_ * T_ * O_;         // (B,T,H) z_seq region

  // Phase 1: x_proj = x @ Wi^T + bi  -> stored into z region (same size)
  gemm_bt_f32<<<dim3((B_ * T_) / 128, H_ / 128), 256, 0, stream>>>(
      x, Wi, bi, z, B_ * T_, H_, N_);

  // Phase 2: recurrence, overwrites xp with z in place
  elman_recurrence<<<B_, 1024, 0, stream>>>(z, h0, w);

  // Phase 3: logits = z @ Wo^T + bo -> out region
  gemm_bt_f32<<<dim3((B_ * T_) / 128, O_ / 128), 256, 0, stream>>>(
      z, Wo, bo, out, B_ * T_, O_, H_);

  // Phase 4: softmax rows in place
  softmax_rows<<<(B_ * T_) / 4, 256, 0, stream>>>(out, B_ * T_);
}